// Round 5
// baseline (611.295 us; speedup 1.0000x reference)
//
#include <hip/hip_runtime.h>
#include <math.h>

// CausalAttention: B=4, S=4096, DIN=DOUT=768, fp32 in/out, bf16 MFMA compute.
// ws layout: [0,256) unused | xb bf16 | q bf16 (pre-scaled) | k bf16 |
//            vT bf16 [b][d][s] | Wt bf16 (3x transposed W)

typedef unsigned short u16;
typedef unsigned int u32;
typedef __attribute__((ext_vector_type(8))) __bf16 bf8;
typedef __attribute__((ext_vector_type(4))) float f32x4;
typedef __attribute__((ext_vector_type(16))) float f32x16;

struct __align__(8) U4 { u16 x, y, z, w; };

#define LOG2E 1.4426950408889634f
#define QSCALE 0.03608439182435161f   // 1/sqrt(768)

#define SBAR() __builtin_amdgcn_s_barrier()
#define WAIT_LGKM0() asm volatile("s_waitcnt lgkmcnt(0)" ::: "memory")
#define WAIT_VM18() asm volatile("s_waitcnt vmcnt(18)" ::: "memory")
#define WAIT_VM6() asm volatile("s_waitcnt vmcnt(6)" ::: "memory")
#define WAIT_VM0() asm volatile("s_waitcnt vmcnt(0)" ::: "memory")

__device__ __forceinline__ u16 f2bf(float f) {
  u32 u = __builtin_bit_cast(u32, f);
  u += 0x7FFFu + ((u >> 16) & 1u);      // RNE
  return (u16)(u >> 16);
}
__device__ __forceinline__ f32x4 mfma16(bf8 a, bf8 b, f32x4 c) {
  return __builtin_amdgcn_mfma_f32_16x16x32_bf16(a, b, c, 0, 0, 0);
}
__device__ __forceinline__ f32x16 mfma32(bf8 a, bf8 b, f32x16 c) {
  return __builtin_amdgcn_mfma_f32_32x32x16_bf16(a, b, c, 0, 0, 0);
}
__device__ __forceinline__ void stage16(const void* g, void* l) {
  __builtin_amdgcn_global_load_lds((const __attribute__((address_space(1))) void*)g,
                                   (__attribute__((address_space(3))) void*)l, 16, 0, 0);
}
// XOR swizzle for gemm (128B rows): key bits >=7 -> bits 4-6
__device__ __forceinline__ u32 swz7(u32 off) { return off ^ (((off >> 7) & 7u) << 4); }

// ---------------- convert x (fp32 -> bf16), vectorized ----------------
__global__ void cvt_x_kernel(const float* __restrict__ x, u16* __restrict__ xb) {
  int i = blockIdx.x * 256 + threadIdx.x;          // float4 index, exact grid
  float4 v = ((const float4*)x)[i];
  U4 o; o.x = f2bf(v.x); o.y = f2bf(v.y); o.z = f2bf(v.z); o.w = f2bf(v.w);
  ((U4*)xb)[i] = o;
}

// ---------------- convert + transpose W: Wt[z][n][k] = bf16(W_z[k][n]) ----------------
__global__ void cvt_w_kernel(const float* __restrict__ Wq, const float* __restrict__ Wk,
                             const float* __restrict__ Wv, u16* __restrict__ wt) {
  __shared__ float tile[32][33];
  int z = blockIdx.z;
  const float* W = (z == 0) ? Wq : ((z == 1) ? Wk : Wv);
  u16* o = wt + (size_t)z * 589824;
  int n0 = blockIdx.x * 32, k0 = blockIdx.y * 32;
  int c = threadIdx.x & 31, r0 = threadIdx.x >> 5;
#pragma unroll
  for (int p = 0; p < 4; p++) tile[r0 + p * 8][c] = W[(size_t)(k0 + r0 + p * 8) * 768 + n0 + c];
  __syncthreads();
#pragma unroll
  for (int p = 0; p < 4; p++) o[(size_t)(n0 + r0 + p * 8) * 768 + k0 + c] = f2bf(tile[c][r0 + p * 8]);
}

// ---------------- QKV GEMM: C[16384x768] = xb * W_z, 128x128 tile, BK=64 ----------------
__global__ __launch_bounds__(256) void gemm_qkv_kernel(
    const u16* __restrict__ xb, const u16* __restrict__ wt,
    u16* __restrict__ qo, u16* __restrict__ ko, u16* __restrict__ vT) {
  __shared__ char lA[16384];
  __shared__ char lB[16384];
  const int tid = threadIdx.x;
  const int lane = tid & 63, wvid = tid >> 6;
  const int wm = wvid >> 1, wn = wvid & 1;
  const int l15 = lane & 15, lg4 = lane >> 4;
  const int m0 = blockIdx.x * 128;
  const int n0 = blockIdx.y * 128;
  const int z = blockIdx.z;
  const u16* wz = wt + (size_t)z * 589824;

  f32x4 acc[4][4];
#pragma unroll
  for (int rt = 0; rt < 4; rt++)
#pragma unroll
    for (int nt = 0; nt < 4; nt++) acc[rt][nt] = f32x4{0.f, 0.f, 0.f, 0.f};

  for (int kt = 0; kt < 12; kt++) {
#pragma unroll
    for (int i = 0; i < 4; i++) {
      u32 o = (u32)i * 4096u + (u32)wvid * 1024u + (u32)lane * 16u;
      u32 lg = swz7(o);
      u32 row = lg >> 7, kbyt = lg & 127u;
      stage16((const char*)xb + ((size_t)(m0 + row) * 1536 + (size_t)kt * 128 + kbyt),
              lA + (size_t)i * 4096 + (size_t)wvid * 1024);
      stage16((const char*)wz + ((size_t)(n0 + row) * 1536 + (size_t)kt * 128 + kbyt),
              lB + (size_t)i * 4096 + (size_t)wvid * 1024);
    }
    __syncthreads();
#pragma unroll
    for (int kk = 0; kk < 2; kk++) {
      bf8 af[4], bfr[4];
#pragma unroll
      for (int rt = 0; rt < 4; rt++) {
        u32 off = (u32)(wm * 64 + rt * 16 + l15) * 128u + (u32)kk * 64u + (u32)lg4 * 16u;
        af[rt] = *(const bf8*)(const void*)(lA + swz7(off));
      }
#pragma unroll
      for (int nt = 0; nt < 4; nt++) {
        u32 off = (u32)(wn * 64 + nt * 16 + l15) * 128u + (u32)kk * 64u + (u32)lg4 * 16u;
        bfr[nt] = *(const bf8*)(const void*)(lB + swz7(off));
      }
#pragma unroll
      for (int rt = 0; rt < 4; rt++)
#pragma unroll
        for (int nt = 0; nt < 4; nt++) acc[rt][nt] = mfma16(af[rt], bfr[nt], acc[rt][nt]);
    }
    __syncthreads();
  }
  if (z == 2) {
#pragma unroll
    for (int rt = 0; rt < 4; rt++) {
      int m = m0 + wm * 64 + rt * 16 + lg4 * 4;
      int batch = m >> 12;
      int s = m & 4095;
#pragma unroll
      for (int nt = 0; nt < 4; nt++) {
        int col = n0 + wn * 64 + nt * 16 + l15;
        U4 pk;
        pk.x = f2bf(acc[rt][nt][0]); pk.y = f2bf(acc[rt][nt][1]);
        pk.z = f2bf(acc[rt][nt][2]); pk.w = f2bf(acc[rt][nt][3]);
        *(U4*)(vT + ((size_t)batch * 768 + col) * 4096 + s) = pk;
      }
    }
  } else {
    u16* dst = (z == 0) ? qo : ko;
    float scl = (z == 0) ? QSCALE : 1.0f;
#pragma unroll
    for (int rt = 0; rt < 4; rt++)
#pragma unroll
      for (int nt = 0; nt < 4; nt++) {
        int col = n0 + wn * 64 + nt * 16 + l15;
#pragma unroll
        for (int j = 0; j < 4; j++) {
          int m = m0 + wm * 64 + rt * 16 + lg4 * 4 + j;
          dst[(size_t)m * 768 + col] = f2bf(acc[rt][nt][j] * scl);
        }
      }
  }
}

// ---------------- flash attention v5: 8 waves, BQ=32, KBLK=128 ----------------
// Q in REGISTERS (qf[24], rows = qbase+rg*16+l15). K streamed via global_load_lds:
// 4 chunks/tile of [128 keys x 192 d] = 48KB, 3 rotating buffers, 2 ahead,
// counted vmcnt (18/6), raw s_barrier. V prefetched at kt-top (12 loads) so its
// waits never drain the K queue. QK^T 16x16 (rg=wv>>2 rows, cg=wv&3 keys).
// PV 32x32 (wave owns cols [wv*96,+96), acc 3x f32x16). P [32][256B] XOR-swz.
__global__ __attribute__((amdgpu_flat_work_group_size(512, 512)))
__attribute__((amdgpu_waves_per_eu(2, 2))) void attn_kernel(
    const u16* __restrict__ qg, const u16* __restrict__ kg, const u16* __restrict__ vg,
    float* __restrict__ out) {
  __shared__ char Klds[3][49152];
  __shared__ char Plds[8192];
  __shared__ float pm[2][4][16];
  __shared__ float ps[2][4][16];
  __shared__ float mrun_s[32], alpha_s2[32], lrun_s[32];

  const int tid = threadIdx.x;
  const int lane = tid & 63;
  const int wv = tid >> 6;           // 0..7
  const int rg = wv >> 2;            // 0..1
  const int cg = wv & 3;             // 0..3
  const int l15 = lane & 15, lg4 = lane >> 4;
  const int l31 = lane & 31, lh = lane >> 5;

  const int b = blockIdx.x;
  const int batch = (b >> 1) & 3;
  const int qb_i = 127 - (((b >> 3) << 1) + (b & 1));   // biggest first
  const int qbase = qb_i * 32;
  const size_t boff = (size_t)batch * 4096;
  const int ntile = (qb_i >> 2) + 1;
  const int gtot = ntile * 4;

  const u16* kbase = kg + boff * 768;

  // per-thread DMA source offsets: dest linear o in 48KB chunk, 384B rows,
  // source pre-swizzled by ((key&7)<<4) so LDS stays linear
  u32 soff[6];
#pragma unroll
  for (int p = 0; p < 6; p++) {
    u32 o = (u32)p * 8192u + (u32)tid * 16u;
    u32 key = o / 384u;
    u32 dby = (o - key * 384u) ^ ((key & 7u) << 4);
    soff[p] = key * 768u + (dby >> 1);
  }

  // prologue: chunks g0 (d 0..191), g1 (d 192..383); gtot >= 4 always
#pragma unroll
  for (int p = 0; p < 6; p++) stage16(kbase + soff[p], &Klds[0][p * 8192 + tid * 16]);
#pragma unroll
  for (int p = 0; p < 6; p++) stage16(kbase + soff[p] + 192u, &Klds[1][p * 8192 + tid * 16]);

  // Q fragments in registers: row = qbase + rg*16 + l15, 24 k-slices
  bf8 qf[24];
  {
    const u16* qrow = qg + (boff + qbase + rg * 16 + l15) * 768 + lg4 * 8;
#pragma unroll
    for (int t = 0; t < 24; t++) qf[t] = *(const bf8*)(const void*)(qrow + t * 32);
  }
  if (tid < 32) { mrun_s[tid] = -INFINITY; lrun_s[tid] = 0.f; }
  WAIT_LGKM0(); SBAR();

  const u32 kxm = (u32)(l15 & 7) << 4;

  f32x16 acc0, acc1, acc2;
#pragma unroll
  for (int r = 0; r < 16; r++) { acc0[r] = 0.f; acc1[r] = 0.f; acc2[r] = 0.f; }

  for (int kt = 0; kt < ntile; kt++) {
    const int kb = kt * 128;
    // ---- V prefetch (ks 0..3) BEFORE this kt's K-DMA issues ----
    const u16* vbase = vg + ((size_t)batch * 768 + wv * 96 + l31) * 4096 + kb + lh * 8;
    bf8 va[4][3];
#pragma unroll
    for (int ks = 0; ks < 4; ks++)
#pragma unroll
      for (int ct = 0; ct < 3; ct++)
        va[ks][ct] = *(const bf8*)(const void*)(vbase + ks * 16 + ct * 131072);

    f32x4 sv0 = f32x4{0.f, 0.f, 0.f, 0.f}, sv1 = sv0;

#pragma unroll
    for (int c = 0; c < 4; c++) {
      const int g = kt * 4 + c;
      if (g + 1 < gtot) { if (c < 2) { WAIT_VM18(); } else { WAIT_VM6(); } }
      else { WAIT_VM0(); }
      SBAR();                                  // chunk g staged
      {
        const char* kbuf = &Klds[g % 3][0];
        const u32 r0 = (u32)(cg * 32 + l15) * 384u;
        const u32 r1 = r0 + 16u * 384u;
#pragma unroll
        for (int ks = 0; ks < 6; ks++) {
          u32 inr = ((u32)ks * 64u + (u32)lg4 * 16u) ^ kxm;
          bf8 kv0 = *(const bf8*)(const void*)(kbuf + r0 + inr);
          bf8 kv1 = *(const bf8*)(const void*)(kbuf + r1 + inr);
          sv0 = mfma16(qf[c * 6 + ks], kv0, sv0);
          sv1 = mfma16(qf[c * 6 + ks], kv1, sv1);
        }
      }
      WAIT_LGKM0(); SBAR();                    // all reads of this buffer done
      if (g + 2 < gtot) {
        const int g2 = g + 2;
        const int kt1 = g2 >> 2, c1 = g2 & 3;
        const u16* src = kbase + (size_t)(kt1 * 128) * 768 + c1 * 192;
        char* dstb = &Klds[g2 % 3][0];
#pragma unroll
        for (int p = 0; p < 6; p++) stage16(src + soff[p], dstb + p * 8192 + tid * 16);
      }
    }

    // causal mask (only last tile crosses the diagonal)
    if (kt == ntile - 1) {
      const int rowg = qbase + rg * 16 + lg4 * 4;
      const int col0 = kb + cg * 32 + l15;
#pragma unroll
      for (int j = 0; j < 4; j++) {
        if (col0 > rowg + j) sv0[j] = -INFINITY;
        if (col0 + 16 > rowg + j) sv1[j] = -INFINITY;
      }
    }
    // per-row max over this wave's 32 keys
    float rmax[4];
#pragma unroll
    for (int j = 0; j < 4; j++) {
      float m = fmaxf(sv0[j], sv1[j]);
      m = fmaxf(m, __shfl_xor(m, 1));
      m = fmaxf(m, __shfl_xor(m, 2));
      m = fmaxf(m, __shfl_xor(m, 4));
      m = fmaxf(m, __shfl_xor(m, 8));
      rmax[j] = m;
    }
    if (l15 == 0) {
#pragma unroll
      for (int j = 0; j < 4; j++) pm[rg][cg][lg4 * 4 + j] = rmax[j];
    }
    WAIT_LGKM0(); SBAR();                      // b1: pm visible
    if (cg == 0 && lg4 == 0) {                 // single-writer combine (16 lanes/rg)
      const int myrow = rg * 16 + l15;
      float mo = mrun_s[myrow];
      float mn = fmaxf(fmaxf(pm[rg][0][l15], pm[rg][1][l15]),
                       fmaxf(pm[rg][2][l15], pm[rg][3][l15]));
      mn = fmaxf(mo, mn);
      alpha_s2[myrow] = exp2f((mo - mn) * LOG2E);
      mrun_s[myrow] = mn;
    }
    WAIT_LGKM0(); SBAR();                      // b2: mrun/alpha visible
    // p = exp(s-m), write P (bf16, swizzled), partial row sums
    {
      const int prow0 = rg * 16 + lg4 * 4;
      float psum[4];
#pragma unroll
      for (int j = 0; j < 4; j++) {
        const int r = prow0 + j;
        const float mrow = mrun_s[r];
        float p0 = exp2f((sv0[j] - mrow) * LOG2E);
        float p1 = exp2f((sv1[j] - mrow) * LOG2E);
        u32 rb = (u32)r * 256u;
        u32 msk = (u32)(r & 7) << 4;
        *(u16*)(void*)(Plds + rb + (((u32)(cg * 32 + l15) * 2u) ^ msk)) = f2bf(p0);
        *(u16*)(void*)(Plds + rb + (((u32)(cg * 32 + 16 + l15) * 2u) ^ msk)) = f2bf(p1);
        float su = p0 + p1;
        su += __shfl_xor(su, 1);
        su += __shfl_xor(su, 2);
        su += __shfl_xor(su, 4);
        su += __shfl_xor(su, 8);
        psum[j] = su;
      }
      if (l15 == 0) {
#pragma unroll
        for (int j = 0; j < 4; j++) ps[rg][cg][lg4 * 4 + j] = psum[j];
      }
    }
    // rescale O accumulators (rows per 32x32 C-layout)
    {
      float al[16];
#pragma unroll
      for (int r = 0; r < 16; r++) al[r] = alpha_s2[(r & 3) + 8 * (r >> 2) + 4 * lh];
#pragma unroll
      for (int r = 0; r < 16; r++) { acc0[r] *= al[r]; acc1[r] *= al[r]; acc2[r] *= al[r]; }
    }
    WAIT_LGKM0(); SBAR();                      // b3: P + ps visible
    if (cg == 0 && lg4 == 0) {
      const int myrow = rg * 16 + l15;
      lrun_s[myrow] = lrun_s[myrow] * alpha_s2[myrow] +
                      ps[rg][0][l15] + ps[rg][1][l15] + ps[rg][2][l15] + ps[rg][3][l15];
    }
    // ---- PV: O[32 x 96] += P[32x128] * V[128x96], 32x32 MFMA, rolling V ----
#pragma unroll
    for (int ks = 0; ks < 8; ks++) {
      u32 paddr = (u32)l31 * 256u + ((((u32)ks * 32u + (u32)lh * 16u)) ^ (((u32)(l31 & 7)) << 4));
      bf8 pa = *(const bf8*)(const void*)(Plds + paddr);
      acc0 = mfma32(pa, va[ks & 3][0], acc0);
      acc1 = mfma32(pa, va[ks & 3][1], acc1);
      acc2 = mfma32(pa, va[ks & 3][2], acc2);
      if (ks < 4) {
#pragma unroll
        for (int ct = 0; ct < 3; ct++)
          va[ks][ct] = *(const bf8*)(const void*)(vbase + (ks + 4) * 16 + ct * 131072);
      }
    }
  }
  WAIT_LGKM0(); SBAR();                        // lrun final visible
  // ---- epilogue: normalize and store fp32 (32x32 C-layout) ----
  float inv[16];
#pragma unroll
  for (int r = 0; r < 16; r++) inv[r] = 1.f / lrun_s[(r & 3) + 8 * (r >> 2) + 4 * lh];
#pragma unroll
  for (int r = 0; r < 16; r++) {
    const int row = (r & 3) + 8 * (r >> 2) + 4 * lh;
    size_t o = (boff + (size_t)(qbase + row)) * 768 + wv * 96 + l31;
    out[o] = acc0[r] * inv[r];
    out[o + 32] = acc1[r] * inv[r];
    out[o + 64] = acc2[r] * inv[r];
  }
}

extern "C" void kernel_launch(void* const* d_in, const int* in_sizes, int n_in,
                              void* d_out, int out_size, void* d_ws, size_t ws_size,
                              hipStream_t stream) {
  const float* x  = (const float*)d_in[0];
  const float* Wq = (const float*)d_in[1];
  const float* Wk = (const float*)d_in[2];
  const float* Wv = (const float*)d_in[3];
  float* out = (float*)d_out;

  char* ws = (char*)d_ws;
  u16* xb = (u16*)(ws + 256);
  u16* qb = xb + 12582912;
  u16* kb = qb + 12582912;
  u16* vT = kb + 12582912;
  u16* wt = vT + 12582912;     // 3 x 589824

  cvt_x_kernel<<<12288, 256, 0, stream>>>(x, xb);
  cvt_w_kernel<<<dim3(24, 24, 3), 256, 0, stream>>>(Wq, Wk, Wv, wt);
  gemm_qkv_kernel<<<dim3(128, 6, 3), 256, 0, stream>>>(xb, wt, qb, kb, vT);
  attn_kernel<<<512, 512, 0, stream>>>(qb, kb, vT, out);
}